// Round 2
// 214.336 us; speedup vs baseline: 1.0447x; 1.0447x over previous
//
#include <hip/hip_runtime.h>
#include <hip/hip_bf16.h>
#include <stdint.h>

// Problem constants
#define NFEAT 4096   // IN_FEATURES == OUT_FEATURES
#define MROWS 1024   // batch
// K (top-k) = 41, ALPHA_LR = 0.01, NUM_DYKSTRA_ITER = 50

typedef __bf16 bf16x8 __attribute__((ext_vector_type(8)));
typedef float  f32x4  __attribute__((ext_vector_type(4)));

__device__ __forceinline__ unsigned short bf16_rne(float f) {
    unsigned int u = __float_as_uint(f);
    unsigned int r = (u + 0x7fffu + ((u >> 16) & 1u)) >> 16;
    return (unsigned short)r;
}

#define GLDS(src, dst) \
    __builtin_amdgcn_global_load_lds((__attribute__((address_space(1))) const void*)(src), \
                                     (__attribute__((address_space(3))) void*)(dst), 16, 0, 0)

// ---------------- Kernel 1: Dykstra soft top-k (1 block) ----------------
__global__ __launch_bounds__(256) void dykstra_kernel(const float* __restrict__ alpha,
                                                      float* __restrict__ g) {
    __shared__ float red[8];
    const int tid = threadIdx.x;
    float y[16], p[16], q[16], yp[16];
    #pragma unroll
    for (int j = 0; j < 16; ++j) {
        y[j] = alpha[tid + 256 * j] / 0.01f;   // y0 = x / l
        p[j] = 0.0f;
        q[j] = 0.0f;
    }
    for (int it = 0; it < 50; ++it) {
        float s = 0.0f;
        #pragma unroll
        for (int j = 0; j < 16; ++j) { yp[j] = y[j] + p[j]; s += yp[j]; }
        #pragma unroll
        for (int off = 32; off > 0; off >>= 1) s += __shfl_down(s, off, 64);
        const int half = (it & 1) * 4;          // WAR-safe double buffer
        if ((tid & 63) == 0) red[half + (tid >> 6)] = s;
        __syncthreads();
        const float S = (red[half] + red[half + 1]) + (red[half + 2] + red[half + 3]);
        const float shift = (S - 41.0f) / 4096.0f;  // (sum - k) / n
        #pragma unroll
        for (int j = 0; j < 16; ++j) {
            float y_hp = yp[j] - shift;
            p[j] = yp[j] - y_hp;            // NOT folded to 'shift' (fp semantics)
            float yq = y_hp + q[j];
            float yb = fminf(fmaxf(yq, 0.0f), 1.0f);
            q[j] = yq - yb;
            y[j] = yb;
        }
    }
    #pragma unroll
    for (int j = 0; j < 16; ++j) g[tid + 256 * j] = y[j];
}

// ---------------- Kernel 2: cvt x->bf16 + materialize W in bf16 -------------
// Each of 1024 blocks first converts its 16 KB slice of x, then builds a
// 256(r) x 64(c) tile of W[r,c] = g[(r-c)%n] * V[(r-c)%n, c].
// LDS band stride padded to 66 elems: write-phase anti-diagonal reads were
// 4-way bank-conflicted at stride 64 (drb step === 0 mod 32); at 66 they are
// <=2-way (free, m136).
__global__ __launch_bounds__(256) void build_w_kernel(const float* __restrict__ V,
                                                      const float* __restrict__ g,
                                                      const float* __restrict__ x,
                                                      unsigned short* __restrict__ xb,
                                                      unsigned short* __restrict__ Wb) {
    __shared__ unsigned short vb[319 * 66];   // ~42 KB bf16, already *g
    const int tid = threadIdx.x;
    const int bid = blockIdx.y * 64 + blockIdx.x;
    // --- cvt slice: 4096 floats per block ---
    {
        const size_t base = (size_t)bid * 4096 + (size_t)tid * 16;
        float4 a0 = *(const float4*)(x + base);
        float4 a1 = *(const float4*)(x + base + 4);
        float4 a2 = *(const float4*)(x + base + 8);
        float4 a3 = *(const float4*)(x + base + 12);
        uint4 s0, s1;
        s0.x = bf16_rne(a0.x) | ((unsigned)bf16_rne(a0.y) << 16);
        s0.y = bf16_rne(a0.z) | ((unsigned)bf16_rne(a0.w) << 16);
        s0.z = bf16_rne(a1.x) | ((unsigned)bf16_rne(a1.y) << 16);
        s0.w = bf16_rne(a1.z) | ((unsigned)bf16_rne(a1.w) << 16);
        s1.x = bf16_rne(a2.x) | ((unsigned)bf16_rne(a2.y) << 16);
        s1.y = bf16_rne(a2.z) | ((unsigned)bf16_rne(a2.w) << 16);
        s1.z = bf16_rne(a3.x) | ((unsigned)bf16_rne(a3.y) << 16);
        s1.w = bf16_rne(a3.z) | ((unsigned)bf16_rne(a3.w) << 16);
        *(uint4*)(xb + base)     = s0;
        *(uint4*)(xb + base + 8) = s1;
    }
    // --- band load: 319 rows x 16 float4, premultiplied by g ---
    const int c0 = blockIdx.x * 64;
    const int r0 = blockIdx.y * 256;
    const int i0 = (r0 - c0 - 63) & 4095;
    #pragma unroll
    for (int j = 0; j < 20; ++j) {
        int idx = tid + 256 * j;
        if (idx < 5104) {
            int t   = idx >> 4;
            int col = (idx & 15) << 2;
            int i   = (i0 + t) & 4095;
            float gv = g[i];
            float4 v = *(const float4*)(V + (size_t)i * NFEAT + c0 + col);
            uint2 pk;
            pk.x = bf16_rne(v.x * gv) | ((unsigned)bf16_rne(v.y * gv) << 16);
            pk.y = bf16_rne(v.z * gv) | ((unsigned)bf16_rne(v.w * gv) << 16);
            *(uint2*)(vb + t * 66 + col) = pk;
        }
    }
    __syncthreads();
    const int dcp = tid & 15;       // col group: cols 4*dcp .. 4*dcp+3
    const int drb = tid >> 4;       // 16 rows per pass
    #pragma unroll
    for (int j = 0; j < 16; ++j) {
        int dr = drb + 16 * j;
        int c  = dcp * 4;
        int tb = dr - c + 63;       // in [3, 318]
        unsigned short w0 = vb[tb * 66 + c];
        unsigned short w1 = vb[(tb - 1) * 66 + c + 1];
        unsigned short w2 = vb[(tb - 2) * 66 + c + 2];
        unsigned short w3 = vb[(tb - 3) * 66 + c + 3];
        uint2 st;
        st.x = w0 | ((unsigned)w1 << 16);
        st.y = w2 | ((unsigned)w3 << 16);
        *(uint2*)(Wb + (size_t)(r0 + dr) * NFEAT + c0 + c) = st;
    }
}

// ---------------- Kernel 3: split-K GEMM, 256x256x32 ----------------
// v3: counted-vmcnt pipeline (T3/T4), WAR race from v2 FIXED.
// v2 bug: stage(kt+3) was issued BEFORE BAR(kt); buf[(kt+3)&3]==buf[(kt-1)&3]
// and a slower wave could still be ds_read-ing that buffer in compute(kt-1)
// -> absmax 1.3e-2. Fix: per iteration order is
//     s_waitcnt vmcnt(8) ; s_barrier ; stage(kt+3) ; compute(kt)
// WAR: stage(kt+3) issues after BAR(kt); every wave finished compute(kt-1)'s
//   ds_reads before reaching BAR(kt) (reads are lgkm-drained into regs before
//   the MFMAs that precede the barrier). Max barrier skew is 1 iter; the
//   fast wave's stage target (kt+3)&3 != slow wave's read target kt&3.
// RAW: at the wait, outstanding = tiles {kt,kt+1,kt+2} = 12 loads/wave;
//   vmcnt(8) retires exactly tile kt's 4 loads; BAR(kt) publishes all waves'
//   portions. 8 loads stay in flight across every barrier (never 0).
// Each tile's loads age 3 full compute phases (~460 cyc) before the wait ->
// L2/HBM latency hidden even at 1 block/CU.
// 512 threads = 8 waves (4m x 2n), wave = 64m x 128n, acc 4x8 f32x4.
// LDS [buf4][kg(4)][row(256)][8] for A and B = 128 KB. Grid (16,4,4) = 256
// blocks = 1/CU; same-n0 blocks share an XCD (B slab L2-resident).
__global__ __launch_bounds__(512, 2) void gemm_kernel(const unsigned short* __restrict__ A,
                                                      const unsigned short* __restrict__ B,
                                                      float* __restrict__ C0,
                                                      float* __restrict__ Cp) {
    __shared__ unsigned short As[4][8192];   // 16 KB per buf
    __shared__ unsigned short Bs[4][8192];
    const int tid  = threadIdx.x;
    const int lane = tid & 63;
    const int w    = tid >> 6;       // 0..7
    const int wm   = w & 3;          // m strip (64 rows)
    const int wn   = w >> 2;         // n strip (128 cols)
    const int m0   = blockIdx.y * 256;
    const int n0   = blockIdx.x * 256;
    const int kbase = blockIdx.z * 1024;   // 32 iters x BK=32

    f32x4 acc[4][8];
    #pragma unroll
    for (int i = 0; i < 4; ++i)
        #pragma unroll
        for (int j = 0; j < 8; ++j)
            acc[i][j] = (f32x4){0.f, 0.f, 0.f, 0.f};

    // staging: wave w covers kg = w&3, row-quarters rq = (w>>2)*2 + {0,1}
    const int kgS = w & 3;
    const int rqB = (w >> 2) * 2;
    const unsigned short* aS = A + (size_t)(m0 + rqB * 64 + lane) * NFEAT + kbase + kgS * 8;
    const unsigned short* bS = B + (size_t)(n0 + rqB * 64 + lane) * NFEAT + kbase + kgS * 8;
    const int dOff = kgS * 2048 + rqB * 512;   // elems; +512 for second rq

    const int kg4 = lane >> 4;
    const int lm  = lane & 15;
    const int aOff = kg4 * 2048 + (wm * 64 + lm) * 8;
    const int bOff = kg4 * 2048 + (wn * 128 + lm) * 8;

    // stage tile kt into buf[kt&3]: 4 GLDS per thread (4 per wave in vmcnt)
    auto stage = [&](int kt) {
        const int ko = kt * 32;
        const int nb = kt & 3;
        GLDS(aS + ko,              As[nb] + dOff);
        GLDS(aS + ko + 64 * NFEAT, As[nb] + dOff + 512);
        GLDS(bS + ko,              Bs[nb] + dOff);
        GLDS(bS + ko + 64 * NFEAT, Bs[nb] + dOff + 512);
    };
    // compute tile kt from buf[kt&3]; compiler inserts fine lgkmcnt waits
    auto compute = [&](int kt) {
        const unsigned short* aRd = As[kt & 3] + aOff;
        const unsigned short* bRd = Bs[kt & 3] + bOff;
        bf16x8 af[4], bfv[8];
        #pragma unroll
        for (int mi = 0; mi < 4; ++mi) af[mi]  = *(const bf16x8*)(aRd + mi * 128);
        #pragma unroll
        for (int ni = 0; ni < 8; ++ni) bfv[ni] = *(const bf16x8*)(bRd + ni * 128);
        __builtin_amdgcn_s_setprio(1);
        #pragma unroll
        for (int mi = 0; mi < 4; ++mi)
            #pragma unroll
            for (int ni = 0; ni < 8; ++ni)
                acc[mi][ni] = __builtin_amdgcn_mfma_f32_16x16x32_bf16(af[mi], bfv[ni],
                                                                      acc[mi][ni], 0, 0, 0);
        __builtin_amdgcn_s_setprio(0);
    };

    stage(0); stage(1); stage(2);          // prologue: 12 loads in flight
    #pragma unroll 1
    for (int kt = 0; kt < 29; ++kt) {
        asm volatile("s_waitcnt vmcnt(8)" ::: "memory");   // tile kt landed (own wave)
        __builtin_amdgcn_s_barrier();                       // all waves' tile kt visible
        __builtin_amdgcn_sched_barrier(0);                  // pin: nothing hoists above BAR
        stage(kt + 3);                      // overwrites buf[(kt-1)&3]: safe post-BAR(kt)
        compute(kt);
    }
    // drain tail: tiles 29, 30, 31 already staged; outstanding = 12
    asm volatile("s_waitcnt vmcnt(8)" ::: "memory");
    __builtin_amdgcn_s_barrier();
    __builtin_amdgcn_sched_barrier(0);
    compute(29);
    asm volatile("s_waitcnt vmcnt(4)" ::: "memory");
    __builtin_amdgcn_s_barrier();
    __builtin_amdgcn_sched_barrier(0);
    compute(30);
    asm volatile("s_waitcnt vmcnt(0)" ::: "memory");
    __builtin_amdgcn_s_barrier();
    __builtin_amdgcn_sched_barrier(0);
    compute(31);

    float* Cz = (blockIdx.z == 0) ? C0 : (Cp + (size_t)(blockIdx.z - 1) * MROWS * NFEAT);
    // C/D layout: col = lane&15, row = (lane>>4)*4 + reg  (m89-verified)
    const int crow = m0 + wm * 64 + (lane >> 4) * 4;
    const int ccol = n0 + wn * 128 + lm;
    #pragma unroll
    for (int mi = 0; mi < 4; ++mi)
        #pragma unroll
        for (int ni = 0; ni < 8; ++ni) {
            float* cp = Cz + (size_t)(crow + mi * 16) * NFEAT + ccol + ni * 16;
            #pragma unroll
            for (int r = 0; r < 4; ++r)
                cp[(size_t)r * NFEAT] = acc[mi][ni][r];
        }
}

// ---------------- Kernel 4: split-K reduce: out += sum of partials ----------
__global__ __launch_bounds__(256) void reduce_kernel(float* __restrict__ out,
                                                     const float* __restrict__ Cp) {
    const size_t i = (size_t)(blockIdx.x * 256 + threadIdx.x) * 4;
    float4 a = *(const float4*)(out + i);
    #pragma unroll
    for (int s = 0; s < 3; ++s) {
        float4 b = *(const float4*)(Cp + (size_t)s * MROWS * NFEAT + i);
        a.x += b.x; a.y += b.y; a.z += b.z; a.w += b.w;
    }
    *(float4*)(out + i) = a;
}

extern "C" void kernel_launch(void* const* d_in, const int* in_sizes, int n_in,
                              void* d_out, int out_size, void* d_ws, size_t ws_size,
                              hipStream_t stream) {
    const float* x     = (const float*)d_in[0];   // (1024, 4096) fp32
    const float* V     = (const float*)d_in[1];   // (4096, 4096) fp32
    const float* alpha = (const float*)d_in[2];   // (4096,) fp32
    float* out = (float*)d_out;                   // (1024, 4096) fp32

    char* ws = (char*)d_ws;
    const size_t xb_off = 16384;
    const size_t wb_off = xb_off + (size_t)MROWS * NFEAT * 2;   // + 8 MB
    const size_t cp_off = wb_off + (size_t)NFEAT * NFEAT * 2;   // +32 MB
    float* g           = (float*)ws;
    unsigned short* xb = (unsigned short*)(ws + xb_off);
    unsigned short* Wb = (unsigned short*)(ws + wb_off);
    float* Cp          = (float*)(ws + cp_off);                 // 48 MB (S=4)
    // ws_size >= 152 MB confirmed empirically (r5 ran S=8 = cp_off + 112 MB).

    hipLaunchKernelGGL(dykstra_kernel, dim3(1),        dim3(256), 0, stream, alpha, g);
    hipLaunchKernelGGL(build_w_kernel, dim3(64, 16),   dim3(256), 0, stream, V, g, x, xb, Wb);
    hipLaunchKernelGGL(gemm_kernel,    dim3(16, 4, 4), dim3(512), 0, stream, xb, Wb, out, Cp);
    hipLaunchKernelGGL(reduce_kernel,  dim3(MROWS * NFEAT / (256 * 4)), dim3(256), 0, stream,
                       out, Cp);
}

// Round 3
// 212.728 us; speedup vs baseline: 1.0526x; 1.0076x over previous
//
#include <hip/hip_runtime.h>
#include <hip/hip_bf16.h>
#include <stdint.h>

// Problem constants
#define NFEAT 4096   // IN_FEATURES == OUT_FEATURES
#define MROWS 1024   // batch
// K (top-k) = 41, ALPHA_LR = 0.01, NUM_DYKSTRA_ITER = 50

typedef __bf16 bf16x8 __attribute__((ext_vector_type(8)));
typedef float  f32x4  __attribute__((ext_vector_type(4)));

__device__ __forceinline__ unsigned short bf16_rne(float f) {
    unsigned int u = __float_as_uint(f);
    unsigned int r = (u + 0x7fffu + ((u >> 16) & 1u)) >> 16;
    return (unsigned short)r;
}

#define GLDS(src, dst) \
    __builtin_amdgcn_global_load_lds((__attribute__((address_space(1))) const void*)(src), \
                                     (__attribute__((address_space(3))) void*)(dst), 16, 0, 0)

// ---------------- Kernel 1: Dykstra soft top-k (1 block) ----------------
__global__ __launch_bounds__(256) void dykstra_kernel(const float* __restrict__ alpha,
                                                      float* __restrict__ g) {
    __shared__ float red[8];
    const int tid = threadIdx.x;
    float y[16], p[16], q[16], yp[16];
    #pragma unroll
    for (int j = 0; j < 16; ++j) {
        y[j] = alpha[tid + 256 * j] / 0.01f;   // y0 = x / l
        p[j] = 0.0f;
        q[j] = 0.0f;
    }
    for (int it = 0; it < 50; ++it) {
        float s = 0.0f;
        #pragma unroll
        for (int j = 0; j < 16; ++j) { yp[j] = y[j] + p[j]; s += yp[j]; }
        #pragma unroll
        for (int off = 32; off > 0; off >>= 1) s += __shfl_down(s, off, 64);
        const int half = (it & 1) * 4;          // WAR-safe double buffer
        if ((tid & 63) == 0) red[half + (tid >> 6)] = s;
        __syncthreads();
        const float S = (red[half] + red[half + 1]) + (red[half + 2] + red[half + 3]);
        const float shift = (S - 41.0f) / 4096.0f;  // (sum - k) / n
        #pragma unroll
        for (int j = 0; j < 16; ++j) {
            float y_hp = yp[j] - shift;
            p[j] = yp[j] - y_hp;            // NOT folded to 'shift' (fp semantics)
            float yq = y_hp + q[j];
            float yb = fminf(fmaxf(yq, 0.0f), 1.0f);
            q[j] = yq - yb;
            y[j] = yb;
        }
    }
    #pragma unroll
    for (int j = 0; j < 16; ++j) g[tid + 256 * j] = y[j];
}

// ---------------- Kernel 2: cvt x->bf16 + materialize W in bf16 -------------
// Each of 1024 blocks first converts its 16 KB slice of x, then builds a
// 256(r) x 64(c) tile of W[r,c] = g[(r-c)%n] * V[(r-c)%n, c].
// LDS band stride padded to 66 elems: write-phase anti-diagonal reads were
// 4-way bank-conflicted at stride 64 (drb step === 0 mod 32); at 66 they are
// <=2-way (free, m136).
__global__ __launch_bounds__(256) void build_w_kernel(const float* __restrict__ V,
                                                      const float* __restrict__ g,
                                                      const float* __restrict__ x,
                                                      unsigned short* __restrict__ xb,
                                                      unsigned short* __restrict__ Wb) {
    __shared__ unsigned short vb[319 * 66];   // ~42 KB bf16, already *g
    const int tid = threadIdx.x;
    const int bid = blockIdx.y * 64 + blockIdx.x;
    // --- cvt slice: 4096 floats per block ---
    {
        const size_t base = (size_t)bid * 4096 + (size_t)tid * 16;
        float4 a0 = *(const float4*)(x + base);
        float4 a1 = *(const float4*)(x + base + 4);
        float4 a2 = *(const float4*)(x + base + 8);
        float4 a3 = *(const float4*)(x + base + 12);
        uint4 s0, s1;
        s0.x = bf16_rne(a0.x) | ((unsigned)bf16_rne(a0.y) << 16);
        s0.y = bf16_rne(a0.z) | ((unsigned)bf16_rne(a0.w) << 16);
        s0.z = bf16_rne(a1.x) | ((unsigned)bf16_rne(a1.y) << 16);
        s0.w = bf16_rne(a1.z) | ((unsigned)bf16_rne(a1.w) << 16);
        s1.x = bf16_rne(a2.x) | ((unsigned)bf16_rne(a2.y) << 16);
        s1.y = bf16_rne(a2.z) | ((unsigned)bf16_rne(a2.w) << 16);
        s1.z = bf16_rne(a3.x) | ((unsigned)bf16_rne(a3.y) << 16);
        s1.w = bf16_rne(a3.z) | ((unsigned)bf16_rne(a3.w) << 16);
        *(uint4*)(xb + base)     = s0;
        *(uint4*)(xb + base + 8) = s1;
    }
    // --- band load: 319 rows x 16 float4, premultiplied by g ---
    const int c0 = blockIdx.x * 64;
    const int r0 = blockIdx.y * 256;
    const int i0 = (r0 - c0 - 63) & 4095;
    #pragma unroll
    for (int j = 0; j < 20; ++j) {
        int idx = tid + 256 * j;
        if (idx < 5104) {
            int t   = idx >> 4;
            int col = (idx & 15) << 2;
            int i   = (i0 + t) & 4095;
            float gv = g[i];
            float4 v = *(const float4*)(V + (size_t)i * NFEAT + c0 + col);
            uint2 pk;
            pk.x = bf16_rne(v.x * gv) | ((unsigned)bf16_rne(v.y * gv) << 16);
            pk.y = bf16_rne(v.z * gv) | ((unsigned)bf16_rne(v.w * gv) << 16);
            *(uint2*)(vb + t * 66 + col) = pk;
        }
    }
    __syncthreads();
    const int dcp = tid & 15;       // col group: cols 4*dcp .. 4*dcp+3
    const int drb = tid >> 4;       // 16 rows per pass
    #pragma unroll
    for (int j = 0; j < 16; ++j) {
        int dr = drb + 16 * j;
        int c  = dcp * 4;
        int tb = dr - c + 63;       // in [3, 318]
        unsigned short w0 = vb[tb * 66 + c];
        unsigned short w1 = vb[(tb - 1) * 66 + c + 1];
        unsigned short w2 = vb[(tb - 2) * 66 + c + 2];
        unsigned short w3 = vb[(tb - 3) * 66 + c + 3];
        uint2 st;
        st.x = w0 | ((unsigned)w1 << 16);
        st.y = w2 | ((unsigned)w3 << 16);
        *(uint2*)(Wb + (size_t)(r0 + dr) * NFEAT + c0 + c) = st;
    }
}

// ---------------- Kernel 3: split-K GEMM, 256x256x32 ----------------
// v4: T3 phase-split on top of v3's counted-vmcnt (T4). v3 measured 65us,
// MfmaUtil 20% -- the monolithic {12 ds_read -> lgkm -> 32 MFMA} burst per
// K-step serializes the LDS and MFMA pipes (m233's 2-phase stall). Now each
// K-step is 4 phases of 8 MFMA:
//   P0: read af0-3,b0,b1; stage A(kt+3); BAR; lgkm0; MFMA ni{0,1}
//   P1: read b2,b3;       stage B(kt+3); BAR; lgkm0; MFMA ni{2,3}
//   P2: read b4,b5,b6,b7;               BAR; lgkm0; MFMA ni{4,5}
//   P3: vmcnt(8);                       BAR;        MFMA ni{6,7}
// Race proof (v2's lesson -- prove the WAR edge at every barrier):
//  * P3's barrier is the only one a stage into buf[kt&3] can follow (fast
//    wave's stage(kt+4) in P0(kt+1)). b6,b7 are read EARLY in P2 and drained
//    by P2's lgkmcnt(0) BEFORE P2's MFMAs -> zero LDS reads in flight across
//    P3's barrier. All other reads of buf[kt&3] drained by their own phase's
//    lgkm0. Stage targets (kt+1..3)&3 never alias the live read buffer.
//  * RAW: at P3's vmcnt(8): outstanding = tiles kt+1,kt+2,kt+3 = 12 loads;
//    retire 4 oldest = tile kt+1; BAR publishes across waves. Never 0 in
//    steady state. Tail: vmcnt(4), vmcnt(0), none.
// 512 threads = 8 waves (4m x 2n), wave = 64m x 128n, acc 4x8 f32x4.
// LDS [buf4][kg(4)][row(256)][8] for A and B = 128 KB. Grid (16,4,4) = 256
// blocks = 1/CU; same-n0 blocks share an XCD (B slab L2-resident).
__global__ __launch_bounds__(512, 2) void gemm_kernel(const unsigned short* __restrict__ A,
                                                      const unsigned short* __restrict__ B,
                                                      float* __restrict__ C0,
                                                      float* __restrict__ Cp) {
    __shared__ unsigned short As[4][8192];   // 16 KB per buf
    __shared__ unsigned short Bs[4][8192];
    const int tid  = threadIdx.x;
    const int lane = tid & 63;
    const int w    = tid >> 6;       // 0..7
    const int wm   = w & 3;          // m strip (64 rows)
    const int wn   = w >> 2;         // n strip (128 cols)
    const int m0   = blockIdx.y * 256;
    const int n0   = blockIdx.x * 256;
    const int kbase = blockIdx.z * 1024;   // 32 iters x BK=32

    f32x4 acc[4][8];
    #pragma unroll
    for (int i = 0; i < 4; ++i)
        #pragma unroll
        for (int j = 0; j < 8; ++j)
            acc[i][j] = (f32x4){0.f, 0.f, 0.f, 0.f};

    // staging: wave w covers kg = w&3, row-quarters rq = (w>>2)*2 + {0,1}
    const int kgS = w & 3;
    const int rqB = (w >> 2) * 2;
    const unsigned short* aS = A + (size_t)(m0 + rqB * 64 + lane) * NFEAT + kbase + kgS * 8;
    const unsigned short* bS = B + (size_t)(n0 + rqB * 64 + lane) * NFEAT + kbase + kgS * 8;
    const int dOff = kgS * 2048 + rqB * 512;   // elems; +512 for second rq

    const int kg4 = lane >> 4;
    const int lm  = lane & 15;
    const int aOff = kg4 * 2048 + (wm * 64 + lm) * 8;
    const int bOff = kg4 * 2048 + (wn * 128 + lm) * 8;

    // full-tile stage (prologue only)
    auto stage = [&](int kt) {
        const int ko = kt * 32;
        const int nb = kt & 3;
        GLDS(aS + ko,              As[nb] + dOff);
        GLDS(aS + ko + 64 * NFEAT, As[nb] + dOff + 512);
        GLDS(bS + ko,              Bs[nb] + dOff);
        GLDS(bS + ko + 64 * NFEAT, Bs[nb] + dOff + 512);
    };

#define MMA8(B0, B1, NI0, NI1)                                                              \
    __builtin_amdgcn_s_setprio(1);                                                          \
    acc[0][NI0] = __builtin_amdgcn_mfma_f32_16x16x32_bf16(af0, B0, acc[0][NI0], 0, 0, 0);   \
    acc[1][NI0] = __builtin_amdgcn_mfma_f32_16x16x32_bf16(af1, B0, acc[1][NI0], 0, 0, 0);   \
    acc[2][NI0] = __builtin_amdgcn_mfma_f32_16x16x32_bf16(af2, B0, acc[2][NI0], 0, 0, 0);   \
    acc[3][NI0] = __builtin_amdgcn_mfma_f32_16x16x32_bf16(af3, B0, acc[3][NI0], 0, 0, 0);   \
    acc[0][NI1] = __builtin_amdgcn_mfma_f32_16x16x32_bf16(af0, B1, acc[0][NI1], 0, 0, 0);   \
    acc[1][NI1] = __builtin_amdgcn_mfma_f32_16x16x32_bf16(af1, B1, acc[1][NI1], 0, 0, 0);   \
    acc[2][NI1] = __builtin_amdgcn_mfma_f32_16x16x32_bf16(af2, B1, acc[2][NI1], 0, 0, 0);   \
    acc[3][NI1] = __builtin_amdgcn_mfma_f32_16x16x32_bf16(af3, B1, acc[3][NI1], 0, 0, 0);   \
    __builtin_amdgcn_s_setprio(0)

#define KSTEP(KT, STAGE_EN, VMSTMT) do {                                                    \
    const int _kt = (KT);                                                                   \
    const unsigned short* aRd = As[_kt & 3] + aOff;                                         \
    const unsigned short* bRd = Bs[_kt & 3] + bOff;                                         \
    bf16x8 af0, af1, af2, af3, p0, p1, p2, p3, p4, p5, p6, p7;                              \
    af0 = *(const bf16x8*)(aRd);        af1 = *(const bf16x8*)(aRd + 128);                  \
    af2 = *(const bf16x8*)(aRd + 256);  af3 = *(const bf16x8*)(aRd + 384);                  \
    p0  = *(const bf16x8*)(bRd);        p1  = *(const bf16x8*)(bRd + 128);                  \
    if (STAGE_EN) {                                                                         \
        const int _ko = (_kt + 3) * 32;  const int _nb = (_kt + 3) & 3;                     \
        GLDS(aS + _ko,              As[_nb] + dOff);                                        \
        GLDS(aS + _ko + 64 * NFEAT, As[_nb] + dOff + 512);                                  \
    }                                                                                       \
    __builtin_amdgcn_s_barrier();                                                           \
    asm volatile("s_waitcnt lgkmcnt(0)" ::: "memory");                                      \
    __builtin_amdgcn_sched_barrier(0);                                                      \
    MMA8(p0, p1, 0, 1);                                                                     \
    p2 = *(const bf16x8*)(bRd + 256);   p3 = *(const bf16x8*)(bRd + 384);                   \
    if (STAGE_EN) {                                                                         \
        const int _ko = (_kt + 3) * 32;  const int _nb = (_kt + 3) & 3;                     \
        GLDS(bS + _ko,              Bs[_nb] + dOff);                                        \
        GLDS(bS + _ko + 64 * NFEAT, Bs[_nb] + dOff + 512);                                  \
    }                                                                                       \
    __builtin_amdgcn_s_barrier();                                                           \
    asm volatile("s_waitcnt lgkmcnt(0)" ::: "memory");                                      \
    __builtin_amdgcn_sched_barrier(0);                                                      \
    MMA8(p2, p3, 2, 3);                                                                     \
    p4 = *(const bf16x8*)(bRd + 512);   p5 = *(const bf16x8*)(bRd + 640);                   \
    p6 = *(const bf16x8*)(bRd + 768);   p7 = *(const bf16x8*)(bRd + 896);                   \
    __builtin_amdgcn_s_barrier();                                                           \
    asm volatile("s_waitcnt lgkmcnt(0)" ::: "memory");                                      \
    __builtin_amdgcn_sched_barrier(0);                                                      \
    MMA8(p4, p5, 4, 5);                                                                     \
    VMSTMT;                                                                                 \
    __builtin_amdgcn_s_barrier();                                                           \
    __builtin_amdgcn_sched_barrier(0);                                                      \
    MMA8(p6, p7, 6, 7);                                                                     \
} while (0)

    stage(0); stage(1); stage(2);          // prologue: 12 loads in flight
    asm volatile("s_waitcnt vmcnt(8)" ::: "memory");   // tile 0 landed
    __builtin_amdgcn_s_barrier();                       // published to all waves
    #pragma unroll 1
    for (int kt = 0; kt < 29; ++kt) {
        KSTEP(kt, 1, asm volatile("s_waitcnt vmcnt(8)" ::: "memory"));
    }
    KSTEP(29, 0, asm volatile("s_waitcnt vmcnt(4)" ::: "memory"));
    KSTEP(30, 0, asm volatile("s_waitcnt vmcnt(0)" ::: "memory"));
    KSTEP(31, 0, (void)0);

    float* Cz = (blockIdx.z == 0) ? C0 : (Cp + (size_t)(blockIdx.z - 1) * MROWS * NFEAT);
    // C/D layout: col = lane&15, row = (lane>>4)*4 + reg  (m89-verified)
    const int crow = m0 + wm * 64 + (lane >> 4) * 4;
    const int ccol = n0 + wn * 128 + lm;
    #pragma unroll
    for (int mi = 0; mi < 4; ++mi)
        #pragma unroll
        for (int ni = 0; ni < 8; ++ni) {
            float* cp = Cz + (size_t)(crow + mi * 16) * NFEAT + ccol + ni * 16;
            #pragma unroll
            for (int r = 0; r < 4; ++r)
                cp[(size_t)r * NFEAT] = acc[mi][ni][r];
        }
}

// ---------------- Kernel 4: split-K reduce: out += sum of partials ----------
__global__ __launch_bounds__(256) void reduce_kernel(float* __restrict__ out,
                                                     const float* __restrict__ Cp) {
    const size_t i = (size_t)(blockIdx.x * 256 + threadIdx.x) * 4;
    float4 a = *(const float4*)(out + i);
    #pragma unroll
    for (int s = 0; s < 3; ++s) {
        float4 b = *(const float4*)(Cp + (size_t)s * MROWS * NFEAT + i);
        a.x += b.x; a.y += b.y; a.z += b.z; a.w += b.w;
    }
    *(float4*)(out + i) = a;
}

extern "C" void kernel_launch(void* const* d_in, const int* in_sizes, int n_in,
                              void* d_out, int out_size, void* d_ws, size_t ws_size,
                              hipStream_t stream) {
    const float* x     = (const float*)d_in[0];   // (1024, 4096) fp32
    const float* V     = (const float*)d_in[1];   // (4096, 4096) fp32
    const float* alpha = (const float*)d_in[2];   // (4096,) fp32
    float* out = (float*)d_out;                   // (1024, 4096) fp32

    char* ws = (char*)d_ws;
    const size_t xb_off = 16384;
    const size_t wb_off = xb_off + (size_t)MROWS * NFEAT * 2;   // + 8 MB
    const size_t cp_off = wb_off + (size_t)NFEAT * NFEAT * 2;   // +32 MB
    float* g           = (float*)ws;
    unsigned short* xb = (unsigned short*)(ws + xb_off);
    unsigned short* Wb = (unsigned short*)(ws + wb_off);
    float* Cp          = (float*)(ws + cp_off);                 // 48 MB (S=4)
    // ws_size >= 152 MB confirmed empirically (r5 ran S=8 = cp_off + 112 MB).

    hipLaunchKernelGGL(dykstra_kernel, dim3(1),        dim3(256), 0, stream, alpha, g);
    hipLaunchKernelGGL(build_w_kernel, dim3(64, 16),   dim3(256), 0, stream, V, g, x, xb, Wb);
    hipLaunchKernelGGL(gemm_kernel,    dim3(16, 4, 4), dim3(512), 0, stream, xb, Wb, out, Cp);
    hipLaunchKernelGGL(reduce_kernel,  dim3(MROWS * NFEAT / (256 * 4)), dim3(256), 0, stream,
                       out, Cp);
}